// Round 6
// baseline (258.399 us; speedup 1.0000x reference)
//
#include <hip/hip_runtime.h>
#include <hip/hip_bf16.h>

// ---------- types / helpers ----------
typedef __attribute__((ext_vector_type(8))) short bh8;   // 8 bf16 bit patterns (4 VGPRs)
typedef __attribute__((ext_vector_type(4))) float fx4;

#define GLOAD16(g, l)                                                          \
  __builtin_amdgcn_global_load_lds(                                            \
      (const __attribute__((address_space(1))) void*)(g),                      \
      (__attribute__((address_space(3))) void*)(l), 16, 0, 0)

__device__ __forceinline__ unsigned short f2bf(float f) {
  unsigned int u = __float_as_uint(f);
  u += 0x7fffu + ((u >> 16) & 1u);     // RNE
  return (unsigned short)(u >> 16);
}
__device__ __forceinline__ float bf2f(short h) {
  return __uint_as_float(((unsigned int)(unsigned short)h) << 16);
}

// ---------- kernel 1: transpose + f32->bf16 convert ----------
__global__ __launch_bounds__(256) void transpose_cvt(
    const float* __restrict__ in, short* __restrict__ out, int R, int Ccols) {
  __shared__ float tile[64][65];
  const int b = blockIdx.z;
  const int c0 = blockIdx.x * 64;
  const int r0 = blockIdx.y * 64;
  const float* ip = in + (size_t)b * R * Ccols;
  short* op = out + (size_t)b * Ccols * R;
  const int tid = threadIdx.x;
  const int tx = tid & 63, ty = tid >> 6;
#pragma unroll
  for (int i = 0; i < 16; ++i) {
    int r = ty + i * 4;
    tile[tx][r] = ip[(size_t)(r0 + r) * Ccols + c0 + tx];
  }
  __syncthreads();
  const int cg = tid & 15;
  const int rr = tid >> 4;
#pragma unroll
  for (int i = 0; i < 4; ++i) {
    const int cc = i * 16 + rr;
    const unsigned int lo = (unsigned int)f2bf(tile[cc][cg * 4 + 0]) |
                            ((unsigned int)f2bf(tile[cc][cg * 4 + 1]) << 16);
    const unsigned int hi = (unsigned int)f2bf(tile[cc][cg * 4 + 2]) |
                            ((unsigned int)f2bf(tile[cc][cg * 4 + 3]) << 16);
    uint2 v; v.x = lo; v.y = hi;
    *(uint2*)&op[(size_t)(c0 + cc) * R + r0 + cg * 4] = v;
  }
}

// ---------- GEMM: C = A(MxKC) * Bt(NxKC)^T, bf16 in, fp32 accum ----------
// 256x256 tile, BK=32, 8 waves (2M x 4N), per-wave 128x64 out (acc[8][4]).
// Phase-interleaved schedule (T3/T4): 2 phases per K-tile, each phase =
// {ds_read frag subtile | stage 2 global_load_lds | barrier | lgkm(0) |
//  setprio(1) 16xMFMA setprio(0) | barrier}.
// vmcnt(2) ONCE per group, after issuing phase-0's 2 stage loads: per-wave
// outstanding = 4(tile g) + 2(new) -> wait to <=2 certifies tile g while the
// pipe never drains; the following s_barrier makes certification collective.
// Streaming operand staged at phase 0 (2-phase latency cover), L2-resident
// operand at phase 1 (MODE1: A=X streams, B=WinT 1.5MB L2-hot; MODE2
// swapped: B=AO streams, A=WoutT hot).
// LDS chunk swizzle (verified 0-conflict in r4/r5): LDS[row][c] holds global
// k-chunk c ^ ((row>>1)&3); staged via pre-swizzled global source (linear
// GLOAD dest, rule #21), read back with the same XOR.
template <int MODE, int KC>
__global__ __launch_bounds__(512, 2) void gemm_bt(
    const short* __restrict__ A, const short* __restrict__ Bt,
    const float* __restrict__ bias, void* __restrict__ Cout,
    int M, int N, int tok0) {
  __shared__ short As[2][8192] __attribute__((aligned(16)));  // 2 x 256x32
  __shared__ short Bs[2][8192] __attribute__((aligned(16)));
  constexpr int NT = KC / 32;
  const int tid = threadIdx.x;
  const int lane = tid & 63;
  const int wv = tid >> 6;     // 0..7
  const int wm = wv >> 2;      // 0..1  (M half)
  const int wn = wv & 3;       // 0..3  (N quarter)

  // ---- XCD-aware swizzle (bijective when nwg % 8 == 0) ----
  const int nbx = gridDim.x, nby = gridDim.y;
  const int nwg = nbx * nby;
  int h = blockIdx.y * nbx + blockIdx.x;
  int L = h;
  if ((nwg & 7) == 0) {
    const int q = nwg >> 3;
    L = (h & 7) * q + (h >> 3);
  }
  const int bx = L / nby;            // consecutive L share bx (B panel)
  const int by = L - bx * nby;
  const int m0 = by * 256, n0 = bx * 256;

  const int lr = lane & 15;
  const int kg = lane >> 4;                       // k-chunk 0..3
  const int rsw = (kg ^ ((lr >> 1) & 3)) * 8;     // swizzled read chunk (shorts)

  const int srow = tid >> 2;                      // 0..127
  const int schunk = ((tid & 3) ^ ((tid >> 3) & 3)) * 8;  // pre-swizzled src k
  const size_t abase = (size_t)(m0 + srow) * KC + schunk;
  const size_t bbase = (size_t)(n0 + srow) * KC + schunk;
  const int doff = tid * 16;                      // linear LDS dest (bytes)

  // stage half hh (rows hh*128..+127) of K-tile kt into buffer b
#define SA(kt, b, hh)                                                          \
  GLOAD16(A + abase + (size_t)(hh)*128 * KC + (kt)*32,                         \
          (char*)&As[b][0] + (hh)*8192 + doff)
#define SB(kt, b, hh)                                                          \
  GLOAD16(Bt + bbase + (size_t)(hh)*128 * KC + (kt)*32,                        \
          (char*)&Bs[b][0] + (hh)*8192 + doff)

  fx4 acc[8][4] = {};

  // prologue: K-tile 0 -> buf0 (4 issues/wave in flight)
  SA(0, 0, 0); SA(0, 0, 1); SB(0, 0, 0); SB(0, 0, 1);

#define MF16(a0_, a1_, a2_, a3_, r0_)                                          \
  {                                                                            \
    _Pragma("unroll") for (int j = 0; j < 4; ++j) {                            \
      acc[r0_ + 0][j] =                                                        \
          __builtin_amdgcn_mfma_f32_16x16x32_bf16(a0_, bb[j], acc[r0_ + 0][j], 0, 0, 0); \
      acc[r0_ + 1][j] =                                                        \
          __builtin_amdgcn_mfma_f32_16x16x32_bf16(a1_, bb[j], acc[r0_ + 1][j], 0, 0, 0); \
      acc[r0_ + 2][j] =                                                        \
          __builtin_amdgcn_mfma_f32_16x16x32_bf16(a2_, bb[j], acc[r0_ + 2][j], 0, 0, 0); \
      acc[r0_ + 3][j] =                                                        \
          __builtin_amdgcn_mfma_f32_16x16x32_bf16(a3_, bb[j], acc[r0_ + 3][j], 0, 0, 0); \
    }                                                                          \
  }

  for (int g = 0; g < NT; ++g) {
    const int buf = g & 1, nb = buf ^ 1;
    const short* Ab = &As[buf][0];
    const short* Bb = &Bs[buf][0];

    // ---------------- phase 0 (mh = 0) ----------------
    __builtin_amdgcn_sched_barrier(0);
    if (g + 1 < NT) {
      if (MODE == 1) { SA(g + 1, nb, 0); SA(g + 1, nb, 1); }   // streaming op
      else           { SB(g + 1, nb, 0); SB(g + 1, nb, 1); }
      __builtin_amdgcn_sched_barrier(0);
      asm volatile("s_waitcnt vmcnt(2)" ::: "memory");  // certify tile g
    } else {
      asm volatile("s_waitcnt vmcnt(0)" ::: "memory");  // final drain
    }
    __builtin_amdgcn_s_barrier();   // collective certification of buf
    __builtin_amdgcn_sched_barrier(0);
    {
      bh8 a0 = *(const bh8*)&Ab[(wm * 128 + 0 + lr) * 32 + rsw];
      bh8 a1 = *(const bh8*)&Ab[(wm * 128 + 16 + lr) * 32 + rsw];
      bh8 a2 = *(const bh8*)&Ab[(wm * 128 + 32 + lr) * 32 + rsw];
      bh8 a3 = *(const bh8*)&Ab[(wm * 128 + 48 + lr) * 32 + rsw];
      bh8 bb[4];
#pragma unroll
      for (int j = 0; j < 4; ++j)
        bb[j] = *(const bh8*)&Bb[(wn * 64 + j * 16 + lr) * 32 + rsw];
      asm volatile("s_waitcnt lgkmcnt(0)" ::: "memory");
      __builtin_amdgcn_sched_barrier(0);
      __builtin_amdgcn_s_setprio(1);
      MF16(a0, a1, a2, a3, 0);
      __builtin_amdgcn_s_setprio(0);
      __builtin_amdgcn_sched_barrier(0);
      __builtin_amdgcn_s_barrier();

      // ---------------- phase 1 (mh = 1) ----------------
      a0 = *(const bh8*)&Ab[(wm * 128 + 64 + 0 + lr) * 32 + rsw];
      a1 = *(const bh8*)&Ab[(wm * 128 + 64 + 16 + lr) * 32 + rsw];
      a2 = *(const bh8*)&Ab[(wm * 128 + 64 + 32 + lr) * 32 + rsw];
      a3 = *(const bh8*)&Ab[(wm * 128 + 64 + 48 + lr) * 32 + rsw];
      if (g + 1 < NT) {
        if (MODE == 1) { SB(g + 1, nb, 0); SB(g + 1, nb, 1); } // resident op
        else           { SA(g + 1, nb, 0); SA(g + 1, nb, 1); }
      }
      __builtin_amdgcn_sched_barrier(0);
      __builtin_amdgcn_s_barrier();
      asm volatile("s_waitcnt lgkmcnt(0)" ::: "memory");
      __builtin_amdgcn_sched_barrier(0);
      __builtin_amdgcn_s_setprio(1);
      MF16(a0, a1, a2, a3, 4);
      __builtin_amdgcn_s_setprio(0);
      __builtin_amdgcn_sched_barrier(0);
      __builtin_amdgcn_s_barrier();
    }
  }

  if (MODE == 1) {
    short* C = (short*)Cout;
#pragma unroll
    for (int i = 0; i < 8; ++i) {
      const int gm = m0 + wm * 128 + i * 16 + kg * 4;
#pragma unroll
      for (int j = 0; j < 4; ++j) {
        const int gn = n0 + wn * 64 + j * 16 + lr;
        const float bv = bias[gn];
#pragma unroll
        for (int r = 0; r < 4; ++r)
          C[(size_t)(gm + r) * N + gn] = (short)f2bf(acc[i][j][r] + bv);
      }
    }
  } else {
    float* C = (float*)Cout;
#pragma unroll
    for (int i = 0; i < 8; ++i) {
      const int ch0 = m0 + wm * 128 + i * 16 + kg * 4;
#pragma unroll
      for (int j = 0; j < 4; ++j) {
        const int t = tok0 + n0 + wn * 64 + j * 16 + lr;
        const int bb2 = t >> 12, s = t & 4095;
#pragma unroll
        for (int r = 0; r < 4; ++r) {
          const int ch = ch0 + r;
          C[((size_t)(bb2 * 512 + ch)) * 4096 + s] = acc[i][j][r] + bias[ch];
        }
      }
    }
  }
#undef SA
#undef SB
#undef MF16
}

// ---------- attention over heads axis: one wave per token ----------
__global__ __launch_bounds__(256) void attn_kernel(
    const short* __restrict__ QKV, short* __restrict__ AO) {
  __shared__ short sq[4][1536] __attribute__((aligned(16)));
  const int tid = threadIdx.x, lane = tid & 63, wv = tid >> 6;
  const int t = blockIdx.x * 4 + wv;

  {
    const short* g = QKV + (size_t)t * 1536 + lane * 8;
    char* l = (char*)&sq[wv][0];
    GLOAD16(g, l);
    GLOAD16(g + 512, l + 1024);
    GLOAD16(g + 1024, l + 2048);
  }
  asm volatile("s_waitcnt vmcnt(0)" ::: "memory");

  const int i = lane >> 3, j = lane & 7;
  const short* q = &sq[wv][i * 192];
  const short* k = &sq[wv][j * 192 + 64];
  float s = 0.f;
#pragma unroll
  for (int c = 0; c < 8; ++c) {
    bh8 qa = *(const bh8*)&q[c * 8];
    bh8 ka = *(const bh8*)&k[c * 8];
#pragma unroll
    for (int e = 0; e < 8; ++e) s += bf2f(qa[e]) * bf2f(ka[e]);
  }
  s *= 0.125f;

  float m = s;
  m = fmaxf(m, __shfl_xor(m, 1));
  m = fmaxf(m, __shfl_xor(m, 2));
  m = fmaxf(m, __shfl_xor(m, 4));
  float p = __expf(s - m);
  float sum = p;
  sum += __shfl_xor(sum, 1);
  sum += __shfl_xor(sum, 2);
  sum += __shfl_xor(sum, 4);
  const float a = p / sum;

  float o[8] = {};
#pragma unroll
  for (int jj = 0; jj < 8; ++jj) {
    const float aj = __shfl(a, (lane & 56) | jj);
    bh8 va = *(const bh8*)&sq[wv][jj * 192 + 128 + j * 8];
#pragma unroll
    for (int e = 0; e < 8; ++e) o[e] += aj * bf2f(va[e]);
  }
  bh8 ov;
#pragma unroll
  for (int e = 0; e < 8; ++e) ov[e] = (short)f2bf(o[e]);
  *(bh8*)&AO[(size_t)t * 512 + i * 64 + j * 8] = ov;
}

// ---------- launch ----------
extern "C" void kernel_launch(void* const* d_in, const int* in_sizes, int n_in,
                              void* d_out, int out_size, void* d_ws,
                              size_t ws_size, hipStream_t stream) {
  const float* x = (const float*)d_in[0];
  const float* W_in = (const float*)d_in[2];
  const float* b_in = (const float*)d_in[3];
  const float* W_out = (const float*)d_in[4];
  const float* b_out = (const float*)d_in[5];
  float* out = (float*)d_out;

  short* Xbf = (short*)d_ws;
  short* WinT = Xbf + (size_t)32768 * 512;
  short* WoutT = WinT + (size_t)1536 * 512;
  short* QKVc = WoutT + (size_t)512 * 512;

  const size_t fixed_bytes =
      ((size_t)32768 * 512 + (size_t)1536 * 512 + (size_t)512 * 512) * 2;
  int NC = 1;
  while (NC < 128 &&
         fixed_bytes + ((size_t)32768 / NC) * 1536 * 2 > ws_size)
    NC <<= 1;
  const int Mc = 32768 / NC;

  transpose_cvt<<<dim3(64, 8, 8), 256, 0, stream>>>(x, Xbf, 512, 4096);
  transpose_cvt<<<dim3(24, 8, 1), 256, 0, stream>>>(W_in, WinT, 512, 1536);
  transpose_cvt<<<dim3(8, 8, 1), 256, 0, stream>>>(W_out, WoutT, 512, 512);

  for (int c = 0; c < NC; ++c) {
    const int t0 = c * Mc;
    short* Ach = Xbf + (size_t)t0 * 512;
    // GEMM1: QKVc = Ach @ WinT^T + b_in   (M=Mc, N=1536, K=512)
    gemm_bt<1, 512><<<dim3(6, Mc / 256), 512, 0, stream>>>(Ach, WinT, b_in,
                                                           QKVc, Mc, 1536, 0);
    attn_kernel<<<dim3(Mc / 4), 256, 0, stream>>>(QKVc, Ach);
    // GEMM2: out(ch, tok) = WoutT @ AO^T + b_out -> (B,C,S) f32
    gemm_bt<2, 512><<<dim3(Mc / 256, 2), 512, 0, stream>>>(WoutT, Ach, b_out,
                                                           out, 512, Mc, t0);
  }
}

// Round 7
// 256.313 us; speedup vs baseline: 1.0081x; 1.0081x over previous
//
#include <hip/hip_runtime.h>
#include <hip/hip_bf16.h>

// ---------- types / helpers ----------
typedef __attribute__((ext_vector_type(8))) short bh8;   // 8 bf16 bit patterns (4 VGPRs)
typedef __attribute__((ext_vector_type(4))) float fx4;

#define GLOAD16(g, l)                                                          \
  __builtin_amdgcn_global_load_lds(                                            \
      (const __attribute__((address_space(1))) void*)(g),                      \
      (__attribute__((address_space(3))) void*)(l), 16, 0, 0)

__device__ __forceinline__ unsigned short f2bf(float f) {
  unsigned int u = __float_as_uint(f);
  u += 0x7fffu + ((u >> 16) & 1u);     // RNE
  return (unsigned short)(u >> 16);
}
__device__ __forceinline__ float bf2f(short h) {
  return __uint_as_float(((unsigned int)(unsigned short)h) << 16);
}

// ---------- kernel 1: transpose + f32->bf16 convert ----------
__global__ __launch_bounds__(256) void transpose_cvt(
    const float* __restrict__ in, short* __restrict__ out, int R, int Ccols) {
  __shared__ float tile[64][65];
  const int b = blockIdx.z;
  const int c0 = blockIdx.x * 64;
  const int r0 = blockIdx.y * 64;
  const float* ip = in + (size_t)b * R * Ccols;
  short* op = out + (size_t)b * Ccols * R;
  const int tid = threadIdx.x;
  const int tx = tid & 63, ty = tid >> 6;
#pragma unroll
  for (int i = 0; i < 16; ++i) {
    int r = ty + i * 4;
    tile[tx][r] = ip[(size_t)(r0 + r) * Ccols + c0 + tx];
  }
  __syncthreads();
  const int cg = tid & 15;
  const int rr = tid >> 4;
#pragma unroll
  for (int i = 0; i < 4; ++i) {
    const int cc = i * 16 + rr;
    const unsigned int lo = (unsigned int)f2bf(tile[cc][cg * 4 + 0]) |
                            ((unsigned int)f2bf(tile[cc][cg * 4 + 1]) << 16);
    const unsigned int hi = (unsigned int)f2bf(tile[cc][cg * 4 + 2]) |
                            ((unsigned int)f2bf(tile[cc][cg * 4 + 3]) << 16);
    uint2 v; v.x = lo; v.y = hi;
    *(uint2*)&op[(size_t)(c0 + cc) * R + r0 + cg * 4] = v;
  }
}

// ---------- GEMM: C = A(MxKC) * Bt(NxKC)^T, bf16 in, fp32 accum ----------
// Deep-ring schedule, BM=256 BN=128 BK=64, 8 waves (4M x 2N, 64x64/wave).
// LDS 128KB: A-ring 3-deep (96KB, streaming operand, 2-K-step lookahead
// ~1300cyc HBM cover), B-ring 2-deep (32KB, L2/L3-resident operand, 1-step).
// Ledger (per-thread issues: A=4/step, B=2/step; issue order B(s) then A(s+1)
// keeps "newest 4 = A(s+1)"):
//   prologue: B(0),A(0),A(1)  [10 in flight]
//   iter s:  vmcnt(4)  -> newest-4 = A(s+1) may fly; A(s),B(s) certified
//            s_barrier -> cert collective; all waves done reading step s-1
//                         => bufB[(s+1)&1], bufA[(s+2)%3] free to re-stage
//            stage B(s+1)->bufB[(s+1)&1], A(s+2)->bufA[(s+2)%3]
//            compute step s (16 ds_read_b128 + 32 MFMA/wave, no inner barrier)
//   s=NS-1: vmcnt(0) (stale drain: those loads issued >=1 step earlier).
// LDS swizzle (BK=64, 128B row stride): chunk' = c ^ (row&7); within each
// 16-lane read cohort 16 lanes spread over 8 chunk-slots = 2-way (free, m136);
// staged via pre-swizzled global source (linear GLOAD dest, rule #21).
// MODE 1: out bf16 row-major MxN, bias[col]; A streams (X), B resident (WinT).
// MODE 2: rows=channels(512), cols=tokens; out f32 scattered to (B,C,S);
//         bias[row]; A resident (WoutT), B streams-but-L3-hot (AO).
template <int MODE, int KC>
__global__ __launch_bounds__(512, 1) void gemm_bt(
    const short* __restrict__ A, const short* __restrict__ Bt,
    const float* __restrict__ bias, void* __restrict__ Cout,
    int M, int N, int tok0) {
  __shared__ short As[3][256 * 64] __attribute__((aligned(16)));  // 96 KB
  __shared__ short Bs[2][128 * 64] __attribute__((aligned(16)));  // 32 KB
  constexpr int NS = KC / 64;   // 8
  const int tid = threadIdx.x;
  const int lane = tid & 63;
  const int wv = tid >> 6;      // 0..7
  const int wm = wv >> 1;       // 0..3  (M quarter, 64 rows)
  const int wn = wv & 1;        // 0..1  (N half, 64 cols)

  // ---- XCD-aware swizzle (bijective when nwg % 8 == 0) ----
  const int nbx = gridDim.x, nby = gridDim.y;
  const int nwg = nbx * nby;
  int h = blockIdx.y * nbx + blockIdx.x;
  int L = h;
  if ((nwg & 7) == 0) {
    const int q = nwg >> 3;
    L = (h & 7) * q + (h >> 3);
  }
  int bx, by;
  if (MODE == 1) {  // x-fastest: consecutive L share by (A panel = X, streams)
    by = L / nbx;
    bx = L - by * nbx;
  } else {          // y-fastest: consecutive L share bx (B panel = AO)
    bx = L / nby;
    by = L - bx * nby;
  }
  const int m0 = by * 256, n0 = bx * 128;

  const int lr = lane & 15;
  const int kg = lane >> 4;     // 0..3

  // staging: thread covers row (q*64 + tid>>3), 16B chunk (tid&7), with
  // source chunk pre-XORed by row&7 == (tid>>3)&7
  const int schunk = ((tid & 7) ^ ((tid >> 3) & 7)) * 8;   // shorts
  const size_t abase = (size_t)(m0 + (tid >> 3)) * KC + schunk;
  const size_t bbase = (size_t)(n0 + (tid >> 3)) * KC + schunk;

  auto STAGE_A = [&](int s) {
    const int buf = s % 3;
    const size_t ko = (size_t)s * 64;
#pragma unroll
    for (int q = 0; q < 4; ++q)
      GLOAD16(A + abase + (size_t)q * 64 * KC + ko,
              (char*)&As[buf][0] + q * 8192 + tid * 16);
  };
  auto STAGE_B = [&](int s) {
    const int buf = s & 1;
    const size_t ko = (size_t)s * 64;
#pragma unroll
    for (int q = 0; q < 2; ++q)
      GLOAD16(Bt + bbase + (size_t)q * 64 * KC + ko,
              (char*)&Bs[buf][0] + q * 8192 + tid * 16);
  };

  fx4 acc[4][4] = {};

  // prologue: B(0), A(0), A(1)  -> newest 4 outstanding = A(1)
  STAGE_B(0);
  STAGE_A(0);
  STAGE_A(1);

  for (int s = 0; s < NS; ++s) {
    __builtin_amdgcn_sched_barrier(0);
    if (s < NS - 1) {
      asm volatile("s_waitcnt vmcnt(4)" ::: "memory");  // A(s),B(s) certified
    } else {
      asm volatile("s_waitcnt vmcnt(0)" ::: "memory");  // stale drain
    }
    __builtin_amdgcn_s_barrier();
    __builtin_amdgcn_sched_barrier(0);
    if (s + 1 < NS) STAGE_B(s + 1);   // bufB[(s+1)&1]: freed by barrier
    if (s + 2 < NS) STAGE_A(s + 2);   // bufA[(s+2)%3]: freed by barrier
    __builtin_amdgcn_sched_barrier(0);

    const short* Ab = &As[s % 3][0];
    const short* Bb = &Bs[s & 1][0];
#pragma unroll
    for (int kk = 0; kk < 2; ++kk) {
      const int cs = ((kk * 4 + kg) ^ (lr & 7)) * 8;  // swizzled chunk (shorts)
      bh8 af[4], bf[4];
#pragma unroll
      for (int i = 0; i < 4; ++i)
        af[i] = *(const bh8*)&Ab[(wm * 64 + i * 16 + lr) * 64 + cs];
#pragma unroll
      for (int j = 0; j < 4; ++j)
        bf[j] = *(const bh8*)&Bb[(wn * 64 + j * 16 + lr) * 64 + cs];
#pragma unroll
      for (int i = 0; i < 4; ++i)
#pragma unroll
        for (int j = 0; j < 4; ++j)
          acc[i][j] = __builtin_amdgcn_mfma_f32_16x16x32_bf16(
              af[i], bf[j], acc[i][j], 0, 0, 0);
    }
  }

  if (MODE == 1) {
    short* C = (short*)Cout;
#pragma unroll
    for (int i = 0; i < 4; ++i) {
      const int gm = m0 + wm * 64 + i * 16 + kg * 4;
#pragma unroll
      for (int j = 0; j < 4; ++j) {
        const int gn = n0 + wn * 64 + j * 16 + lr;
        const float bv = bias[gn];
#pragma unroll
        for (int r = 0; r < 4; ++r)
          C[(size_t)(gm + r) * N + gn] = (short)f2bf(acc[i][j][r] + bv);
      }
    }
  } else {
    float* C = (float*)Cout;
#pragma unroll
    for (int i = 0; i < 4; ++i) {
      const int ch0 = m0 + wm * 64 + i * 16 + kg * 4;
#pragma unroll
      for (int j = 0; j < 4; ++j) {
        const int t = tok0 + n0 + wn * 64 + j * 16 + lr;
        const int bb2 = t >> 12, sp = t & 4095;
#pragma unroll
        for (int r = 0; r < 4; ++r) {
          const int ch = ch0 + r;
          C[((size_t)(bb2 * 512 + ch)) * 4096 + sp] = acc[i][j][r] + bias[ch];
        }
      }
    }
  }
}

// ---------- attention over heads axis: one wave per token ----------
__global__ __launch_bounds__(256) void attn_kernel(
    const short* __restrict__ QKV, short* __restrict__ AO) {
  __shared__ short sq[4][1536] __attribute__((aligned(16)));
  const int tid = threadIdx.x, lane = tid & 63, wv = tid >> 6;
  const int t = blockIdx.x * 4 + wv;

  {
    const short* g = QKV + (size_t)t * 1536 + lane * 8;
    char* l = (char*)&sq[wv][0];
    GLOAD16(g, l);
    GLOAD16(g + 512, l + 1024);
    GLOAD16(g + 1024, l + 2048);
  }
  asm volatile("s_waitcnt vmcnt(0)" ::: "memory");

  const int i = lane >> 3, j = lane & 7;
  const short* q = &sq[wv][i * 192];
  const short* k = &sq[wv][j * 192 + 64];
  float s = 0.f;
#pragma unroll
  for (int c = 0; c < 8; ++c) {
    bh8 qa = *(const bh8*)&q[c * 8];
    bh8 ka = *(const bh8*)&k[c * 8];
#pragma unroll
    for (int e = 0; e < 8; ++e) s += bf2f(qa[e]) * bf2f(ka[e]);
  }
  s *= 0.125f;

  float m = s;
  m = fmaxf(m, __shfl_xor(m, 1));
  m = fmaxf(m, __shfl_xor(m, 2));
  m = fmaxf(m, __shfl_xor(m, 4));
  float p = __expf(s - m);
  float sum = p;
  sum += __shfl_xor(sum, 1);
  sum += __shfl_xor(sum, 2);
  sum += __shfl_xor(sum, 4);
  const float a = p / sum;

  float o[8] = {};
#pragma unroll
  for (int jj = 0; jj < 8; ++jj) {
    const float aj = __shfl(a, (lane & 56) | jj);
    bh8 va = *(const bh8*)&sq[wv][jj * 192 + 128 + j * 8];
#pragma unroll
    for (int e = 0; e < 8; ++e) o[e] += aj * bf2f(va[e]);
  }
  bh8 ov;
#pragma unroll
  for (int e = 0; e < 8; ++e) ov[e] = (short)f2bf(o[e]);
  *(bh8*)&AO[(size_t)t * 512 + i * 64 + j * 8] = ov;
}

// ---------- launch ----------
extern "C" void kernel_launch(void* const* d_in, const int* in_sizes, int n_in,
                              void* d_out, int out_size, void* d_ws,
                              size_t ws_size, hipStream_t stream) {
  const float* x = (const float*)d_in[0];
  const float* W_in = (const float*)d_in[2];
  const float* b_in = (const float*)d_in[3];
  const float* W_out = (const float*)d_in[4];
  const float* b_out = (const float*)d_in[5];
  float* out = (float*)d_out;

  short* Xbf = (short*)d_ws;
  short* WinT = Xbf + (size_t)32768 * 512;
  short* WoutT = WinT + (size_t)1536 * 512;
  short* QKVc = WoutT + (size_t)512 * 512;

  const size_t fixed_bytes =
      ((size_t)32768 * 512 + (size_t)1536 * 512 + (size_t)512 * 512) * 2;
  int NC = 1;
  while (NC < 64 &&
         fixed_bytes + ((size_t)32768 / NC) * 1536 * 2 > ws_size)
    NC <<= 1;
  const int Mc = 32768 / NC;

  transpose_cvt<<<dim3(64, 8, 8), 256, 0, stream>>>(x, Xbf, 512, 4096);
  transpose_cvt<<<dim3(24, 8, 1), 256, 0, stream>>>(W_in, WinT, 512, 1536);
  transpose_cvt<<<dim3(8, 8, 1), 256, 0, stream>>>(W_out, WoutT, 512, 512);

  for (int c = 0; c < NC; ++c) {
    const int t0 = c * Mc;
    short* Ach = Xbf + (size_t)t0 * 512;
    // GEMM1: QKVc = Ach @ WinT^T + b_in   (M=Mc, N=1536, K=512)
    gemm_bt<1, 512><<<dim3(12, Mc / 256), 512, 0, stream>>>(Ach, WinT, b_in,
                                                            QKVc, Mc, 1536, 0);
    attn_kernel<<<dim3(Mc / 4), 256, 0, stream>>>(QKVc, Ach);
    // GEMM2: out(ch, tok) = WoutT @ AO^T + b_out -> (B,C,S) f32
    gemm_bt<2, 512><<<dim3(Mc / 128, 2), 512, 0, stream>>>(WoutT, Ach, b_out,
                                                           out, 512, Mc, t0);
  }
}